// Round 9
// baseline (154.396 us; speedup 1.0000x reference)
//
#include <hip/hip_runtime.h>
#include <hip/hip_bf16.h>

#define HW 16384   // 128*128
#define CC 64
#define BB 4

typedef __attribute__((ext_vector_type(8))) short bf8;   // 8 bf16 (4 VGPRs)
typedef __attribute__((ext_vector_type(4))) float f4;    // MFMA C/D frag

static __device__ __forceinline__ float bf2f(unsigned short u) {
    return __uint_as_float(((unsigned)u) << 16);
}
static __device__ __forceinline__ unsigned short f2bf(float f) {
    __hip_bfloat16 h = __float2bfloat16(f);   // RNE
    return *reinterpret_cast<unsigned short*>(&h);
}

// ---------------------------------------------------------------------------
// K0: weight repack (blocks 0..215) + x transpose via LDS (blocks 216..1239).
//  wC2 fragment-major conv weights [18432]:
//      wC2[s*1024 + row*32 + quad*8 + j] = w_off[row][c][t],
//      t = s>>1, c = (s&1)*32 + quad*8 + j, rows 27..31 zero.
//      -> A-frag load (fixed s,mt) = 64 lanes x 16B CONTIGUOUS (1KB).
//  W2 fragment-major align weights [36864]:
//      W2[(s*256 + row*4 + quad)*8 + j] = w_align[row][c][t]  (same t,c map)
//  xT [b*HW+hw][c] : channels contiguous (128B rows)
// ---------------------------------------------------------------------------
__global__ __launch_bounds__(256) void k_prep_tx(const float* __restrict__ x,
                                                 const float* __restrict__ w_off,
                                                 const float* __restrict__ w_align,
                                                 unsigned short* __restrict__ xT,
                                                 unsigned short* __restrict__ wC2,
                                                 unsigned short* __restrict__ W2) {
    __shared__ unsigned T32[64 * 33];   // 8448 B
    int bx = blockIdx.x, t = threadIdx.x;
    if (bx < 216) {
        int i = bx * 256 + t;
        if (i < 18432) {
            int j = i & 7, quad = (i >> 3) & 3, row = (i >> 5) & 31, s = i >> 10;
            int c = ((s & 1) << 5) + quad * 8 + j, tt = s >> 1;
            float v = (row < 27) ? w_off[row * 576 + c * 9 + tt] : 0.f;
            wC2[i] = f2bf(v);
        } else {
            int j2 = i - 18432;                   // 0..36863
            int f = j2 >> 3, jj = j2 & 7;
            int s = f >> 8, rem = f & 255;
            int row = rem >> 2, quad = rem & 3;
            int c = ((s & 1) << 5) + quad * 8 + jj;
            int tt = s >> 1;
            W2[j2] = f2bf(w_align[row * 576 + c * 9 + tt]);
        }
        return;
    }
    int pix0 = (bx - 216) * 64;
    int b = pix0 >> 14, hw0 = pix0 & (HW - 1);
    const float* xb = x + (size_t)b * CC * HW + hw0;
#pragma unroll
    for (int u = 0; u < 8; u++) {
        int i = t + 256 * u;                 // 2048 = 32 cp x 64 p
        int cp = i >> 6, p = i & 63;
        float v0 = xb[(size_t)(2 * cp) * HW + p];
        float v1 = xb[(size_t)(2 * cp + 1) * HW + p];
        T32[p * 33 + cp] = (unsigned)f2bf(v0) | ((unsigned)f2bf(v1) << 16);
    }
    __syncthreads();
#pragma unroll
    for (int u = 0; u < 2; u++) {
        int i = t + 256 * u;                 // 512 = 64 p x 8 q
        int p = i >> 3, q = i & 7;
        uint4 qq;
        qq.x = T32[p * 33 + q * 4 + 0];
        qq.y = T32[p * 33 + q * 4 + 1];
        qq.z = T32[p * 33 + q * 4 + 2];
        qq.w = T32[p * 33 + q * 4 + 3];
        *(uint4*)(xT + ((size_t)b * HW + hw0 + p) * CC + q * 8) = qq;
    }
}

// ---------------------------------------------------------------------------
// K1: offset conv, 9-tap shifted MFMA GEMM. No LDS. B-loads batched per
// 3-tap group behind sched_barrier(0); A-frags from fragment-major wC2
// (contiguous 1KB wave-loads, L1-resident).
// ---------------------------------------------------------------------------
__global__ __launch_bounds__(256) void k_conv(const unsigned short* __restrict__ xT,
                                              const unsigned short* __restrict__ wC2,
                                              const float* __restrict__ b_off,
                                              float* __restrict__ off) {
    int t = threadIdx.x, lane = t & 63, wv = t >> 6;
    int quad = lane >> 4, col = lane & 15;
    int n = blockIdx.x * 64 + wv * 16 + col;           // global pixel
    int b = n >> 14, hw = n & (HW - 1), h = hw >> 7, w = hw & 127;
    const unsigned short* xTb = xT + (size_t)b * HW * CC;
    const bf8 zero = {0, 0, 0, 0, 0, 0, 0, 0};

    f4 acc0 = {0.f, 0.f, 0.f, 0.f};
    f4 acc1 = {0.f, 0.f, 0.f, 0.f};
#pragma unroll
    for (int g = 0; g < 3; g++) {
        bf8 bv[3][2];
        bool valid[3];
#pragma unroll
        for (int kk = 0; kk < 3; kk++) {
            int tap = 3 * g + kk;
            int dyt = tap / 3 - 1, dxt = tap - (tap / 3) * 3 - 1;
            int hs = h + dyt, ws = w + dxt;
            valid[kk] = ((unsigned)hs < 128u) && ((unsigned)ws < 128u);
            int hc = min(max(hs, 0), 127), wc = min(max(ws, 0), 127);
            const unsigned short* src = xTb + ((size_t)(hc * 128 + wc)) * CC + quad * 8;
            bv[kk][0] = *(const bf8*)(src);
            bv[kk][1] = *(const bf8*)(src + 32);
        }
        __builtin_amdgcn_sched_barrier(0);   // keep the 6 loads batched
#pragma unroll
        for (int kk = 0; kk < 3; kk++) {
            int tap = 3 * g + kk;
            bf8 b0 = valid[kk] ? bv[kk][0] : zero;
            bf8 b1 = valid[kk] ? bv[kk][1] : zero;
#pragma unroll
            for (int h2 = 0; h2 < 2; h2++) {
                int s = 2 * tap + h2;
                bf8 bb = h2 ? b1 : b0;
                const bf8 a0 = *(const bf8*)(wC2 + (size_t)s * 1024 + col * 32 + quad * 8);
                const bf8 a1 = *(const bf8*)(wC2 + (size_t)s * 1024 + 512 + col * 32 + quad * 8);
                acc0 = __builtin_amdgcn_mfma_f32_16x16x32_bf16(a0, bb, acc0, 0, 0, 0);
                acc1 = __builtin_amdgcn_mfma_f32_16x16x32_bf16(a1, bb, acc1, 0, 0, 0);
            }
        }
    }
#pragma unroll
    for (int i = 0; i < 4; i++) {
        int o0 = quad * 4 + i;                          // 0..15, always < 27
        {
            float v = acc0[i] + b_off[o0];
            if (o0 >= 18) v = 2.f / (1.f + __expf(-v));
            off[((size_t)b * 27 + o0) * HW + hw] = v;
        }
        int o1 = 16 + o0;
        if (o1 < 27) {
            float v = acc1[i] + b_off[o1];
            if (o1 >= 18) v = 2.f / (1.f + __expf(-v));
            off[((size_t)b * 27 + o1) * HW + hw] = v;
        }
    }
}

// ---------------------------------------------------------------------------
// K2 (fused): 4 independent waves/block, wave = 16 px x all 64 outs.
// All 27 off values hoisted to registers (chain-link removed), then per
// 3-tap group: 24 gathers issued together behind sched_barrier(0),
// then lerp + MFMA. B-frags land directly in registers; A-frags from
// fragment-major W2 (contiguous 1KB wave-loads). No LDS, no barriers.
// ---------------------------------------------------------------------------
__global__ __launch_bounds__(256) void k_fused(const unsigned short* __restrict__ xT,
                                               const float* __restrict__ off,
                                               const unsigned short* __restrict__ W2,
                                               const float* __restrict__ b_align,
                                               float* __restrict__ wten) {
    int t = threadIdx.x, lane = t & 63, wv = t >> 6;
    int quad = lane >> 4, col = lane & 15;
    int pix0 = blockIdx.x * 64;
    int b = pix0 >> 14;
    int px = (pix0 & (HW - 1)) + wv * 16 + col;
    int h = px >> 7, w = px & 127;
    const unsigned short* xTb = xT + (size_t)b * HW * CC;
    const float* offp = off + (size_t)b * 27 * HW + px;

    // ---- hoist all 27 offset/mask loads (independent, batched) ----
    float offv[27];
#pragma unroll
    for (int r = 0; r < 27; r++) offv[r] = offp[(size_t)r * HW];
    __builtin_amdgcn_sched_barrier(0);

    f4 acc[4];
#pragma unroll
    for (int mt = 0; mt < 4; mt++) acc[mt] = (f4){0.f, 0.f, 0.f, 0.f};

#pragma unroll
    for (int g = 0; g < 3; g++) {
        uint4 q[3][8];
        float cw[3][4];
#pragma unroll
        for (int kk = 0; kk < 3; kk++) {
            int k = 3 * g + kk;
            float dy = offv[2 * k];
            float dx = offv[2 * k + 1];
            float m  = offv[18 + k];
            int k3 = k / 3;
            float ys = (float)(h + k3 - 1) + dy;
            float xs = (float)(w + (k - 3 * k3) - 1) + dx;
            float y0f = floorf(ys), x0f = floorf(xs);
            float fy = ys - y0f, fx = xs - x0f;
            int y0 = (int)y0f, x0 = (int)x0f;
            int y1 = y0 + 1, x1 = x0 + 1;
            bool vy0 = (unsigned)y0 < 128u, vy1 = (unsigned)y1 < 128u;
            bool vx0 = (unsigned)x0 < 128u, vx1 = (unsigned)x1 < 128u;
            int cy0 = min(max(y0, 0), 127), cy1 = min(max(y1, 0), 127);
            int cx0 = min(max(x0, 0), 127), cx1 = min(max(x1, 0), 127);
            cw[kk][0] = (1.f - fy) * (1.f - fx) * ((vy0 && vx0) ? m : 0.f);
            cw[kk][1] = (1.f - fy) * fx         * ((vy0 && vx1) ? m : 0.f);
            cw[kk][2] = fy * (1.f - fx)         * ((vy1 && vx0) ? m : 0.f);
            cw[kk][3] = fy * fx                 * ((vy1 && vx1) ? m : 0.f);
            const unsigned short* c00 = xTb + ((size_t)(cy0 * 128 + cx0)) * CC + quad * 8;
            const unsigned short* c01 = xTb + ((size_t)(cy0 * 128 + cx1)) * CC + quad * 8;
            const unsigned short* c10 = xTb + ((size_t)(cy1 * 128 + cx0)) * CC + quad * 8;
            const unsigned short* c11 = xTb + ((size_t)(cy1 * 128 + cx1)) * CC + quad * 8;
            q[kk][0] = *(const uint4*)(c00);      q[kk][1] = *(const uint4*)(c01);
            q[kk][2] = *(const uint4*)(c10);      q[kk][3] = *(const uint4*)(c11);
            q[kk][4] = *(const uint4*)(c00 + 32); q[kk][5] = *(const uint4*)(c01 + 32);
            q[kk][6] = *(const uint4*)(c10 + 32); q[kk][7] = *(const uint4*)(c11 + 32);
        }
        __builtin_amdgcn_sched_barrier(0);   // keep the 24 gathers batched
#pragma unroll
        for (int kk = 0; kk < 3; kk++) {
            int k = 3 * g + kk;
            bf8 bfrag[2];
#pragma unroll
            for (int h2 = 0; h2 < 2; h2++) {
                const unsigned short* u00 = (const unsigned short*)&q[kk][h2 * 4 + 0];
                const unsigned short* u01 = (const unsigned short*)&q[kk][h2 * 4 + 1];
                const unsigned short* u10 = (const unsigned short*)&q[kk][h2 * 4 + 2];
                const unsigned short* u11 = (const unsigned short*)&q[kk][h2 * 4 + 3];
                unsigned short ov[8];
#pragma unroll
                for (int j = 0; j < 8; j++) {
                    float v = cw[kk][0] * bf2f(u00[j]) + cw[kk][1] * bf2f(u01[j])
                            + cw[kk][2] * bf2f(u10[j]) + cw[kk][3] * bf2f(u11[j]);
                    ov[j] = f2bf(v);
                }
                bfrag[h2] = *(const bf8*)ov;
            }
#pragma unroll
            for (int h2 = 0; h2 < 2; h2++) {
                int s = 2 * k + h2;
#pragma unroll
                for (int mt = 0; mt < 4; mt++) {
                    bf8 a = *(const bf8*)(W2 + ((size_t)(s * 256 + (mt * 16 + col) * 4 + quad)) * 8);
                    acc[mt] = __builtin_amdgcn_mfma_f32_16x16x32_bf16(a, bfrag[h2], acc[mt], 0, 0, 0);
                }
            }
        }
    }

    // ---- epilogue: bias + exp(sigmoid) ----
    float* wb = wten + (size_t)b * CC * HW + px;
#pragma unroll
    for (int mt = 0; mt < 4; mt++)
#pragma unroll
        for (int i = 0; i < 4; i++) {
            int o = mt * 16 + quad * 4 + i;
            float u = acc[mt][i] + b_align[o];
            float sg = 1.f / (1.f + __expf(-u));
            wb[(size_t)o * HW] = __expf(sg);
        }
}

// ---------------------------------------------------------------------------
// K3: out = pool3s2(w*x)/pool3s2(w) (the /9 cancels; zero-pad taps drop out).
// ---------------------------------------------------------------------------
__global__ __launch_bounds__(256) void k_pool(const float* __restrict__ x,
                                              const float* __restrict__ wten,
                                              float* __restrict__ out) {
    int idx = blockIdx.x * 256 + threadIdx.x;
    int ow = idx & 63;
    int oh = (idx >> 6) & 63;
    int bc = idx >> 12;
    const float* wp = wten + (size_t)bc * HW;
    const float* xp = x + (size_t)bc * HW;
    float num = 0.f, den = 0.f;
#pragma unroll
    for (int iy = 0; iy < 3; iy++) {
        int y = 2 * oh + iy - 1;
        if ((unsigned)y >= 128u) continue;
#pragma unroll
        for (int ix = 0; ix < 3; ix++) {
            int xc = 2 * ow + ix - 1;
            if ((unsigned)xc >= 128u) continue;
            float wv = wp[y * 128 + xc];
            float xv = xp[y * 128 + xc];
            num = fmaf(wv, xv, num);
            den += wv;
        }
    }
    out[idx] = num / den;
}

// ---------------------------------------------------------------------------
extern "C" void kernel_launch(void* const* d_in, const int* in_sizes, int n_in,
                              void* d_out, int out_size, void* d_ws, size_t ws_size,
                              hipStream_t stream) {
    const float* x       = (const float*)d_in[0];
    const float* w_off   = (const float*)d_in[1];
    const float* b_off   = (const float*)d_in[2];
    const float* w_align = (const float*)d_in[3];
    const float* b_align = (const float*)d_in[4];
    float* out = (float*)d_out;

    // workspace layout (~32.4 MB):
    char* p = (char*)d_ws;
    float* off  = (float*)p;                  p += (size_t)BB * 27 * HW * 4;  // 7.08 MB
    float* wten = (float*)p;                  p += (size_t)BB * CC * HW * 4;  // 16.78 MB
    unsigned short* xT  = (unsigned short*)p; p += (size_t)BB * HW * CC * 2;  // 8.39 MB
    unsigned short* wC2 = (unsigned short*)p; p += 18432 * 2;                 // 36.9 KB
    unsigned short* W2  = (unsigned short*)p;                                 // 73.7 KB

    k_prep_tx<<<dim3(1240), dim3(256), 0, stream>>>(x, w_off, w_align, xT, wC2, W2);
    k_conv<<<dim3(1024), dim3(256), 0, stream>>>(xT, wC2, b_off, off);
    k_fused<<<dim3(1024), dim3(256), 0, stream>>>(xT, off, W2, b_align, wten);
    k_pool<<<dim3(4096), dim3(256), 0, stream>>>(x, wten, out);
}

// Round 10
// 137.337 us; speedup vs baseline: 1.1242x; 1.1242x over previous
//
#include <hip/hip_runtime.h>
#include <hip/hip_bf16.h>

#define HW 16384   // 128*128
#define CC 64
#define BB 4

typedef __attribute__((ext_vector_type(8))) short bf8;   // 8 bf16 (4 VGPRs)
typedef __attribute__((ext_vector_type(4))) float f4;    // MFMA C/D frag

static __device__ __forceinline__ float bf2f(unsigned short u) {
    return __uint_as_float(((unsigned)u) << 16);
}
static __device__ __forceinline__ unsigned short f2bf(float f) {
    __hip_bfloat16 h = __float2bfloat16(f);   // RNE
    return *reinterpret_cast<unsigned short*>(&h);
}

// ---------------------------------------------------------------------------
// K0: weight repack (blocks 0..215) + x transpose via LDS (blocks 216..1239).
//  wC2 fragment-major conv weights [18432]:
//      wC2[s*1024 + row*32 + quad*8 + j] = w_off[row][c][t],
//      t = s>>1, c = (s&1)*32 + quad*8 + j, rows 27..31 zero.
//  Wal row-major align weights [64][576]: Wal[o][t*64+c] = w_align[o][c][t]
//  xT [b*HW+hw][c] : channels contiguous (128B rows)
// Transpose blocks use the same XCD swizzle as the merged kernel so the
// xT slice they write stays in the L2 of the XCD that will read it.
// ---------------------------------------------------------------------------
__global__ __launch_bounds__(256) void k_prep_tx(const float* __restrict__ x,
                                                 const float* __restrict__ w_off,
                                                 const float* __restrict__ w_align,
                                                 unsigned short* __restrict__ xT,
                                                 unsigned short* __restrict__ wC2,
                                                 unsigned short* __restrict__ Wal) {
    __shared__ unsigned T32[64 * 33];   // 8448 B
    int bx = blockIdx.x, t = threadIdx.x;
    if (bx < 216) {
        int i = bx * 256 + t;
        if (i < 18432) {
            int j = i & 7, quad = (i >> 3) & 3, row = (i >> 5) & 31, s = i >> 10;
            int c = ((s & 1) << 5) + quad * 8 + j, tt = s >> 1;
            float v = (row < 27) ? w_off[row * 576 + c * 9 + tt] : 0.f;
            wC2[i] = f2bf(v);
        } else {
            int j2 = i - 18432;                   // 0..36863
            int o = j2 / 576, r = j2 - o * 576, tt = r >> 6, c = r & 63;
            Wal[j2] = f2bf(w_align[o * 576 + c * 9 + tt]);
        }
        return;
    }
    int local = bx - 216;                         // 0..1023
    int vb = (local & 7) * 128 + (local >> 3);    // XCD-affinity swizzle
    int pix0 = vb * 64;
    int b = pix0 >> 14, hw0 = pix0 & (HW - 1);
    const float* xb = x + (size_t)b * CC * HW + hw0;
#pragma unroll
    for (int u = 0; u < 8; u++) {
        int i = t + 256 * u;                 // 2048 = 32 cp x 64 p
        int cp = i >> 6, p = i & 63;
        float v0 = xb[(size_t)(2 * cp) * HW + p];
        float v1 = xb[(size_t)(2 * cp + 1) * HW + p];
        T32[p * 33 + cp] = (unsigned)f2bf(v0) | ((unsigned)f2bf(v1) << 16);
    }
    __syncthreads();
#pragma unroll
    for (int u = 0; u < 2; u++) {
        int i = t + 256 * u;                 // 512 = 64 p x 8 q
        int p = i >> 3, q = i & 7;
        uint4 qq;
        qq.x = T32[p * 33 + q * 4 + 0];
        qq.y = T32[p * 33 + q * 4 + 1];
        qq.z = T32[p * 33 + q * 4 + 2];
        qq.w = T32[p * 33 + q * 4 + 3];
        *(uint4*)(xT + ((size_t)b * HW + hw0 + p) * CC + q * 8) = qq;
    }
}

// ---------------------------------------------------------------------------
// K1 (merged): offset-conv MFMA -> offL (LDS) -> sampling -> einsum MFMA
// -> exp(sigmoid) -> wten. Block = 256 threads / 64 px; wave = 16 px x 64 outs.
//  conv phase: 9 regular shifted-row loads (warms L1 for the gathers),
//              A from fragment-major wC2 (global, 36.9 KB, L2-resident).
//  offL[27][64] fp32: per-pixel offset redistribution (broadcast reads).
//  align phase: R6 structure, single-buffer LDS weights per 3-tap group.
// LDS total 32.5 KB -> 5 blocks/CU (20 waves) for latency hiding.
// ---------------------------------------------------------------------------
__global__ __launch_bounds__(256) void k_merged(const unsigned short* __restrict__ xT,
                                                const unsigned short* __restrict__ wC2,
                                                const unsigned short* __restrict__ Wal,
                                                const float* __restrict__ b_off,
                                                const float* __restrict__ b_align,
                                                float* __restrict__ wten) {
    __shared__ __align__(16) unsigned short WB[64 * 200];   // 25600 B
    __shared__ float offL[27][64];                          // 6912 B

    int t = threadIdx.x, lane = t & 63, wv = t >> 6;
    int quad = lane >> 4, col = lane & 15;
    int bxr = blockIdx.x;
    int bx = (bxr & 7) * 128 + (bxr >> 3);        // XCD-affinity swizzle
    int pix0 = bx * 64;
    int b = pix0 >> 14;
    int pl = wv * 16 + col;                       // block-local pixel
    int px = (pix0 & (HW - 1)) + pl;              // pixel within batch image
    int h = px >> 7, w = px & 127;
    const unsigned short* xTb = xT + (size_t)b * HW * CC;
    const bf8 zero = {0, 0, 0, 0, 0, 0, 0, 0};

    // ---- phase 1: offset conv (regular 3x3 shifted-row MFMA GEMM) ----
    f4 c0 = {0.f, 0.f, 0.f, 0.f};
    f4 c1 = {0.f, 0.f, 0.f, 0.f};
#pragma unroll
    for (int tap = 0; tap < 9; tap++) {
        int dyt = tap / 3 - 1, dxt = tap - (tap / 3) * 3 - 1;
        int hs = h + dyt, ws = w + dxt;
        bool valid = ((unsigned)hs < 128u) && ((unsigned)ws < 128u);
        int hc = min(max(hs, 0), 127), wc = min(max(ws, 0), 127);
        const unsigned short* src = xTb + ((size_t)(hc * 128 + wc)) * CC + quad * 8;
        bf8 b0 = *(const bf8*)(src);
        bf8 b1 = *(const bf8*)(src + 32);
        b0 = valid ? b0 : zero;
        b1 = valid ? b1 : zero;
#pragma unroll
        for (int h2 = 0; h2 < 2; h2++) {
            int s = 2 * tap + h2;
            bf8 bb = h2 ? b1 : b0;
            const bf8 a0 = *(const bf8*)(wC2 + (size_t)s * 1024 + col * 32 + quad * 8);
            const bf8 a1 = *(const bf8*)(wC2 + (size_t)s * 1024 + 512 + col * 32 + quad * 8);
            c0 = __builtin_amdgcn_mfma_f32_16x16x32_bf16(a0, bb, c0, 0, 0, 0);
            c1 = __builtin_amdgcn_mfma_f32_16x16x32_bf16(a1, bb, c1, 0, 0, 0);
        }
    }
    // scatter offsets to LDS (C-layout -> per-pixel columns)
#pragma unroll
    for (int i = 0; i < 4; i++) {
        int o0 = quad * 4 + i;                    // 0..15: always dy/dx
        offL[o0][pl] = c0[i] + b_off[o0];
        int o1 = 16 + o0;                         // 16..31
        if (o1 < 27) {
            float v = c1[i] + b_off[o1];
            if (o1 >= 18) v = 2.f / (1.f + __expf(-v));   // mask = 2*sigmoid
            offL[o1][pl] = v;
        }
    }
    __syncthreads();

    // ---- phase 2: sampling + einsum over 3 tap-groups ----
    f4 acc[4];
#pragma unroll
    for (int mt = 0; mt < 4; mt++) acc[mt] = (f4){0.f, 0.f, 0.f, 0.f};

#pragma unroll
    for (int g = 0; g < 3; g++) {
        // stage align-weight group g into WB (rows padded 192->200 bf16)
#pragma unroll
        for (int u = 0; u < 6; u++) {
            int idx = t + 256 * u;               // 1536 = 64 rows x 24 uint4
            int row = idx / 24, jb = idx - row * 24;
            *(uint4*)(&WB[row * 200 + jb * 8]) = ((const uint4*)Wal)[row * 72 + g * 24 + jb];
        }
        __syncthreads();

#pragma unroll
        for (int kk = 0; kk < 3; kk++) {
            int k = 3 * g + kk;
            float dy = offL[2 * k][pl];
            float dx = offL[2 * k + 1][pl];
            float m  = offL[18 + k][pl];
            int k3 = k / 3;
            float ys = (float)(h + k3 - 1) + dy;
            float xs = (float)(w + (k - 3 * k3) - 1) + dx;
            float y0f = floorf(ys), x0f = floorf(xs);
            float fy = ys - y0f, fx = xs - x0f;
            int y0 = (int)y0f, x0 = (int)x0f;
            int y1 = y0 + 1, x1 = x0 + 1;
            bool vy0 = (unsigned)y0 < 128u, vy1 = (unsigned)y1 < 128u;
            bool vx0 = (unsigned)x0 < 128u, vx1 = (unsigned)x1 < 128u;
            int cy0 = min(max(y0, 0), 127), cy1 = min(max(y1, 0), 127);
            int cx0 = min(max(x0, 0), 127), cx1 = min(max(x1, 0), 127);
            float w00 = (1.f - fy) * (1.f - fx) * ((vy0 && vx0) ? m : 0.f);
            float w01 = (1.f - fy) * fx         * ((vy0 && vx1) ? m : 0.f);
            float w10 = fy * (1.f - fx)         * ((vy1 && vx0) ? m : 0.f);
            float w11 = fy * fx                 * ((vy1 && vx1) ? m : 0.f);

            const unsigned short* c00 = xTb + ((size_t)(cy0 * 128 + cx0)) * CC + quad * 8;
            const unsigned short* c01 = xTb + ((size_t)(cy0 * 128 + cx1)) * CC + quad * 8;
            const unsigned short* c10 = xTb + ((size_t)(cy1 * 128 + cx0)) * CC + quad * 8;
            const unsigned short* c11 = xTb + ((size_t)(cy1 * 128 + cx1)) * CC + quad * 8;
            uint4 qa0 = *(const uint4*)(c00),      qa1 = *(const uint4*)(c01);
            uint4 qa2 = *(const uint4*)(c10),      qa3 = *(const uint4*)(c11);
            uint4 qb0 = *(const uint4*)(c00 + 32), qb1 = *(const uint4*)(c01 + 32);
            uint4 qb2 = *(const uint4*)(c10 + 32), qb3 = *(const uint4*)(c11 + 32);

            bf8 bfrag[2];
#pragma unroll
            for (int h2 = 0; h2 < 2; h2++) {
                const unsigned short* u00 = (const unsigned short*)(h2 ? &qb0 : &qa0);
                const unsigned short* u01 = (const unsigned short*)(h2 ? &qb1 : &qa1);
                const unsigned short* u10 = (const unsigned short*)(h2 ? &qb2 : &qa2);
                const unsigned short* u11 = (const unsigned short*)(h2 ? &qb3 : &qa3);
                unsigned short ov[8];
#pragma unroll
                for (int j = 0; j < 8; j++) {
                    float v = w00 * bf2f(u00[j]) + w01 * bf2f(u01[j])
                            + w10 * bf2f(u10[j]) + w11 * bf2f(u11[j]);
                    ov[j] = f2bf(v);
                }
                bfrag[h2] = *(const bf8*)ov;
            }
#pragma unroll
            for (int h2 = 0; h2 < 2; h2++) {
#pragma unroll
                for (int mt = 0; mt < 4; mt++) {
                    const bf8 a = *(const bf8*)(&WB[(size_t)(mt * 16 + col) * 200
                                                + kk * 64 + h2 * 32 + quad * 8]);
                    acc[mt] = __builtin_amdgcn_mfma_f32_16x16x32_bf16(a, bfrag[h2], acc[mt], 0, 0, 0);
                }
            }
        }
        if (g < 2) __syncthreads();   // WB reads done before next staging
    }

    // ---- epilogue: bias + exp(sigmoid) ----
    float* wb = wten + (size_t)b * CC * HW + px;
#pragma unroll
    for (int mt = 0; mt < 4; mt++)
#pragma unroll
        for (int i = 0; i < 4; i++) {
            int o = mt * 16 + quad * 4 + i;
            float u = acc[mt][i] + b_align[o];
            float sg = 1.f / (1.f + __expf(-u));
            wb[(size_t)o * HW] = __expf(sg);
        }
}

// ---------------------------------------------------------------------------
// K2: out = pool3s2(w*x)/pool3s2(w) (the /9 cancels; zero-pad taps drop out).
// Block mapping XCD-swizzled so each block's wten slice sits in the L2 of
// the XCD that produced it: home XCD of pool block = (2b + (sub>>3)) & 7.
// ---------------------------------------------------------------------------
__global__ __launch_bounds__(256) void k_pool(const float* __restrict__ x,
                                              const float* __restrict__ wten,
                                              float* __restrict__ out) {
    int d = blockIdx.x;
    int xg = d & 7, i = d >> 3;                   // xg = target XCD
    int b = xg >> 1, sub_hi = xg & 1;
    int c = i >> 3, sub_lo = i & 7;
    int vb = ((b * 64 + c) * 16) + sub_hi * 8 + sub_lo;
    int idx = vb * 256 + threadIdx.x;
    int ow = idx & 63;
    int oh = (idx >> 6) & 63;
    int bc = idx >> 12;
    const float* wp = wten + (size_t)bc * HW;
    const float* xp = x + (size_t)bc * HW;
    float num = 0.f, den = 0.f;
#pragma unroll
    for (int iy = 0; iy < 3; iy++) {
        int y = 2 * oh + iy - 1;
        if ((unsigned)y >= 128u) continue;
#pragma unroll
        for (int ix = 0; ix < 3; ix++) {
            int xc = 2 * ow + ix - 1;
            if ((unsigned)xc >= 128u) continue;
            float wv = wp[y * 128 + xc];
            float xv = xp[y * 128 + xc];
            num = fmaf(wv, xv, num);
            den += wv;
        }
    }
    out[idx] = num / den;
}

// ---------------------------------------------------------------------------
extern "C" void kernel_launch(void* const* d_in, const int* in_sizes, int n_in,
                              void* d_out, int out_size, void* d_ws, size_t ws_size,
                              hipStream_t stream) {
    const float* x       = (const float*)d_in[0];
    const float* w_off   = (const float*)d_in[1];
    const float* b_off   = (const float*)d_in[2];
    const float* w_align = (const float*)d_in[3];
    const float* b_align = (const float*)d_in[4];
    float* out = (float*)d_out;

    // workspace layout (~25.3 MB):
    char* p = (char*)d_ws;
    float* wten = (float*)p;                  p += (size_t)BB * CC * HW * 4;  // 16.78 MB
    unsigned short* xT  = (unsigned short*)p; p += (size_t)BB * HW * CC * 2;  // 8.39 MB
    unsigned short* wC2 = (unsigned short*)p; p += 18432 * 2;                 // 36.9 KB
    unsigned short* Wal = (unsigned short*)p;                                 // 73.7 KB

    k_prep_tx<<<dim3(1240), dim3(256), 0, stream>>>(x, w_off, w_align, xT, wC2, Wal);
    k_merged<<<dim3(1024), dim3(256), 0, stream>>>(xT, wC2, Wal, b_off, b_align, wten);
    k_pool<<<dim3(4096), dim3(256), 0, stream>>>(x, wten, out);
}